// Round 1
// baseline (6391.397 us; speedup 1.0000x reference)
//
#include <hip/hip_runtime.h>
#include <hip/hip_bf16.h>
#include <math.h>

// Problem constants (reference: B,L,D_MODEL=(2,4096,1024), D_INNER=2048, D_CONV=4)
#define B_SZ 2
#define L_SZ 4096
#define DM   1024   // D_MODEL
#define DI   2048   // D_INNER (H)
#define E_SZ 4096   // 2*D_INNER
#define DC   4

__device__ __forceinline__ float silu_f(float v) {
    return v / (1.0f + __expf(-v));
}

// ---------------------------------------------------------------------------
// Tiled fp32 GEMM: C[m,n] = sum_k A[m,k] * B[n,k]   (both inner-dim contiguous)
// If A_IS_KXM: A stored as (K x M) row-major instead (used for y^T in GEMM2).
// Tile 128x128, BK=16, 256 threads, 8x8 micro-tile per thread.
// ---------------------------------------------------------------------------
template<bool A_IS_KXM>
__global__ __launch_bounds__(256) void gemm_nt(
    const float* __restrict__ A, const float* __restrict__ Bm,
    float* __restrict__ C,
    int lda, int ldb, int ldc,
    long sA, long sB, long sC, int K)
{
    __shared__ float As[16][132];   // [k][m], +4 pad keeps float4 alignment (528B rows)
    __shared__ float Bs[16][132];   // [k][n]

    const float* Ab = A  + (long)blockIdx.z * sA;
    const float* Bb = Bm + (long)blockIdx.z * sB;
    float*       Cb = C  + (long)blockIdx.z * sC;

    const int m0  = blockIdx.x * 128;
    const int n0  = blockIdx.y * 128;
    const int tid = threadIdx.x;
    // wave-aware micro-tile mapping: within a wave, 8x8 (tm,tn) -> 2-way LDS
    // aliasing max on the b128 fragment reads (free per m136)
    const int wave = tid >> 6, lane = tid & 63;
    const int tm8 = ((wave >> 1) * 8 + (lane >> 3)) * 8;
    const int tn8 = ((wave &  1) * 8 + (lane &  7)) * 8;

    const int rA = tid >> 2;           // 0..63
    const int qA = (tid & 3) << 2;     // 0,4,8,12

    float acc[8][8] = {};

    for (int k0 = 0; k0 < K; k0 += 16) {
        if (k0) __syncthreads();
        if (A_IS_KXM) {
            const int kk = tid >> 5;             // 0..7
            const int mc = (tid & 31) << 2;      // 0..124
            *(float4*)&As[kk][mc]     = *(const float4*)&Ab[(long)(k0 + kk)     * lda + m0 + mc];
            *(float4*)&As[kk + 8][mc] = *(const float4*)&Ab[(long)(k0 + kk + 8) * lda + m0 + mc];
        } else {
            float4 v0 = *(const float4*)&Ab[(long)(m0 + rA)      * lda + k0 + qA];
            float4 v1 = *(const float4*)&Ab[(long)(m0 + rA + 64) * lda + k0 + qA];
            As[qA+0][rA]    = v0.x; As[qA+1][rA]    = v0.y; As[qA+2][rA]    = v0.z; As[qA+3][rA]    = v0.w;
            As[qA+0][rA+64] = v1.x; As[qA+1][rA+64] = v1.y; As[qA+2][rA+64] = v1.z; As[qA+3][rA+64] = v1.w;
        }
        {
            float4 w0 = *(const float4*)&Bb[(long)(n0 + rA)      * ldb + k0 + qA];
            float4 w1 = *(const float4*)&Bb[(long)(n0 + rA + 64) * ldb + k0 + qA];
            Bs[qA+0][rA]    = w0.x; Bs[qA+1][rA]    = w0.y; Bs[qA+2][rA]    = w0.z; Bs[qA+3][rA]    = w0.w;
            Bs[qA+0][rA+64] = w1.x; Bs[qA+1][rA+64] = w1.y; Bs[qA+2][rA+64] = w1.z; Bs[qA+3][rA+64] = w1.w;
        }
        __syncthreads();

        #pragma unroll
        for (int k = 0; k < 16; ++k) {
            float4 a0 = *(const float4*)&As[k][tm8];
            float4 a1 = *(const float4*)&As[k][tm8 + 4];
            float4 b0 = *(const float4*)&Bs[k][tn8];
            float4 b1 = *(const float4*)&Bs[k][tn8 + 4];
            float ar[8] = {a0.x,a0.y,a0.z,a0.w,a1.x,a1.y,a1.z,a1.w};
            float br[8] = {b0.x,b0.y,b0.z,b0.w,b1.x,b1.y,b1.z,b1.w};
            #pragma unroll
            for (int i = 0; i < 8; ++i)
                #pragma unroll
                for (int j = 0; j < 8; ++j)
                    acc[i][j] += ar[i] * br[j];
        }
    }

    #pragma unroll
    for (int i = 0; i < 8; ++i) {
        long row = (long)(m0 + tm8 + i) * ldc + n0 + tn8;
        float4 c0 = make_float4(acc[i][0], acc[i][1], acc[i][2], acc[i][3]);
        float4 c1 = make_float4(acc[i][4], acc[i][5], acc[i][6], acc[i][7]);
        *(float4*)&Cb[row]     = c0;
        *(float4*)&Cb[row + 4] = c1;
    }
}

// ---------------------------------------------------------------------------
// Depthwise causal conv (width 4) + SiLU.  xz layout (B, E, L); x channels are
// e in [0, DI).  One thread per 4 consecutive l.
// ---------------------------------------------------------------------------
__global__ __launch_bounds__(256) void conv_silu_k(
    const float* __restrict__ xz, const float* __restrict__ conv_w,
    const float* __restrict__ conv_b, float* __restrict__ xout)
{
    const long gid = (long)blockIdx.x * 256 + threadIdx.x;
    const int  q   = (int)(gid % (L_SZ / 4));
    const long bc  = gid / (L_SZ / 4);
    const int  ch  = (int)(bc % DI);
    const int  b   = (int)(bc / DI);

    const float* row = xz + ((long)b * E_SZ + ch) * L_SZ;
    const int l0 = q * 4;

    float4 cur = *(const float4*)&row[l0];
    float4 prev = q ? *(const float4*)&row[l0 - 4] : make_float4(0.f, 0.f, 0.f, 0.f);

    const float w0 = conv_w[ch*DC+0], w1 = conv_w[ch*DC+1];
    const float w2 = conv_w[ch*DC+2], w3 = conv_w[ch*DC+3];
    const float bias = conv_b[ch];

    float4 o;
    o.x = silu_f(bias + w0*prev.y + w1*prev.z + w2*prev.w + w3*cur.x);
    o.y = silu_f(bias + w0*prev.z + w1*prev.w + w2*cur.x  + w3*cur.y);
    o.z = silu_f(bias + w0*prev.w + w1*cur.x  + w2*cur.y  + w3*cur.z);
    o.w = silu_f(bias + w0*cur.x  + w1*cur.y  + w2*cur.z  + w3*cur.w);

    *(float4*)&xout[((long)b * DI + ch) * L_SZ + l0] = o;
}

// ---------------------------------------------------------------------------
// Direct causal long conv:  y[b,c,l] = sum_{m<=l} x[b,c,m] * k[c, l-m]
// then y = (y + D_skip[c]*x) * silu(z).  One block per (b, ch, 1024-l-tile);
// thread t owns outputs l0+4t..l0+4t+3.  m staged in 256-chunks; k staged in a
// zero-padded 1280-window (zero-fill of negative k-index implements causality).
// Inner loop: per 4 m's -> 1 broadcast b128 (x) + 2 aligned b128 (k) + 16 FMA.
// ---------------------------------------------------------------------------
__global__ __launch_bounds__(256) void longconv_k(
    const float* __restrict__ xbuf, const float* __restrict__ xz,
    const float* __restrict__ k_ssm, const float* __restrict__ D_skip,
    float* __restrict__ ybuf)
{
    __shared__ float Xs[256];
    __shared__ float Ks[1284];

    const int t  = threadIdx.x;
    const int l0 = blockIdx.x * 1024;
    const int ch = blockIdx.y;
    const int b  = blockIdx.z;

    const float* xrow = xbuf + ((long)b * DI + ch) * L_SZ;
    const float* krow = k_ssm + (long)ch * L_SZ;

    float acc0 = 0.f, acc1 = 0.f, acc2 = 0.f, acc3 = 0.f;

    const int nchunks = l0 / 256 + 4;   // m up to l0+1023
    for (int ci = 0; ci < nchunks; ++ci) {
        const int m0 = ci * 256;
        __syncthreads();   // protect LDS reuse across iterations
        Xs[t] = xrow[m0 + t];
        const int kbase = l0 - m0 - 256;
        for (int idx = t; idx < 1284; idx += 256) {
            const int ki = kbase + idx;
            Ks[idx] = (ki >= 0 && ki < L_SZ) ? krow[ki] : 0.0f;
        }
        __syncthreads();

        #pragma unroll 8
        for (int j0 = 0; j0 < 256; j0 += 4) {
            float4 xq = *(const float4*)&Xs[j0];                // broadcast
            const int base = 4 * t + 256 - j0;                  // multiple of 4
            float4 k1 = *(const float4*)&Ks[base];              // Ks[base..base+3]
            float4 k0 = *(const float4*)&Ks[base - 4];          // Ks[base-4..base-1]
            // output c needs Ks[base + c - jj]
            acc0 += xq.x * k1.x; acc1 += xq.x * k1.y; acc2 += xq.x * k1.z; acc3 += xq.x * k1.w;
            acc0 += xq.y * k0.w; acc1 += xq.y * k1.x; acc2 += xq.y * k1.y; acc3 += xq.y * k1.z;
            acc0 += xq.z * k0.z; acc1 += xq.z * k0.w; acc2 += xq.z * k1.x; acc3 += xq.z * k1.y;
            acc0 += xq.w * k0.y; acc1 += xq.w * k0.z; acc2 += xq.w * k0.w; acc3 += xq.w * k1.x;
        }
    }

    // epilogue: + D_skip*x, * silu(z); z is channel DI+ch of xz
    const int l = l0 + 4 * t;
    float4 xv = *(const float4*)&xrow[l];
    const float* zrow = xz + ((long)b * E_SZ + DI + ch) * L_SZ;
    float4 zv = *(const float4*)&zrow[l];
    const float Ds = D_skip[ch];

    float4 o;
    o.x = (acc0 + Ds * xv.x) * silu_f(zv.x);
    o.y = (acc1 + Ds * xv.y) * silu_f(zv.y);
    o.z = (acc2 + Ds * xv.z) * silu_f(zv.z);
    o.w = (acc3 + Ds * xv.w) * silu_f(zv.w);
    *(float4*)&ybuf[((long)b * DI + ch) * L_SZ + l] = o;
}

// ---------------------------------------------------------------------------
extern "C" void kernel_launch(void* const* d_in, const int* in_sizes, int n_in,
                              void* d_out, int out_size, void* d_ws, size_t ws_size,
                              hipStream_t stream)
{
    const float* hidden = (const float*)d_in[0];  // (B, L, DM)
    const float* W_in   = (const float*)d_in[1];  // (E, DM)
    const float* conv_w = (const float*)d_in[2];  // (DI, 4)
    const float* conv_b = (const float*)d_in[3];  // (DI)
    const float* k_ssm  = (const float*)d_in[4];  // (DI, L)
    const float* D_skip = (const float*)d_in[5];  // (DI)
    const float* W_out  = (const float*)d_in[6];  // (DM, DI)
    float* out = (float*)d_out;                   // (B, L, DM)

    // workspace: xz (B,E,L) | x (B,DI,L) | y (B,DI,L)  => 256 MiB fp32
    float* xz   = (float*)d_ws;
    float* xbuf = xz   + (size_t)B_SZ * E_SZ * L_SZ;
    float* ybuf = xbuf + (size_t)B_SZ * DI * L_SZ;

    // 1) xz[b,e,l] = sum_d W_in[e,d] * hidden[b,l,d]
    gemm_nt<false><<<dim3(E_SZ/128, L_SZ/128, B_SZ), 256, 0, stream>>>(
        W_in, hidden, xz,
        /*lda*/DM, /*ldb*/DM, /*ldc*/L_SZ,
        /*sA*/0L, /*sB*/(long)L_SZ*DM, /*sC*/(long)E_SZ*L_SZ, /*K*/DM);

    // 2) depthwise causal conv4 + SiLU -> xbuf
    conv_silu_k<<<dim3((unsigned)((long)B_SZ*DI*(L_SZ/4)/256)), 256, 0, stream>>>(
        xz, conv_w, conv_b, xbuf);

    // 3) long causal conv + D_skip + silu(z) gate -> ybuf (B,DI,L)
    longconv_k<<<dim3(L_SZ/1024, DI, B_SZ), 256, 0, stream>>>(
        xbuf, xz, k_ssm, D_skip, ybuf);

    // 4) out[b,l,d] = sum_h y[b,h,l] * W_out[d,h]   (A = y stored K x M)
    gemm_nt<true><<<dim3(L_SZ/128, DM/128, B_SZ), 256, 0, stream>>>(
        ybuf, W_out, out,
        /*lda*/L_SZ, /*ldb*/DI, /*ldc*/DM,
        /*sA*/(long)DI*L_SZ, /*sB*/0L, /*sC*/(long)L_SZ*DM, /*K*/DI);
}

// Round 2
// 3026.632 us; speedup vs baseline: 2.1117x; 2.1117x over previous
//
#include <hip/hip_runtime.h>
#include <hip/hip_bf16.h>
#include <math.h>

// Problem constants (reference: B,L,D_MODEL=(2,4096,1024), D_INNER=2048, D_CONV=4)
#define B_SZ 2
#define L_SZ 4096
#define DM   1024   // D_MODEL
#define DI   2048   // D_INNER (H)
#define E_SZ 4096   // 2*D_INNER
#define DC   4

__device__ __forceinline__ float silu_f(float v) {
    return v / (1.0f + __expf(-v));
}

// ---------------------------------------------------------------------------
// Tiled fp32 GEMM: C[m,n] = sum_k A[m,k] * B[n,k]   (both inner-dim contiguous)
// If A_IS_KXM: A stored as (K x M) row-major instead (used for y^T in GEMM2).
// Tile 128x128, BK=16, 256 threads, 8x8 micro-tile per thread.
// ---------------------------------------------------------------------------
template<bool A_IS_KXM>
__global__ __launch_bounds__(256) void gemm_nt(
    const float* __restrict__ A, const float* __restrict__ Bm,
    float* __restrict__ C,
    int lda, int ldb, int ldc,
    long sA, long sB, long sC, int K)
{
    __shared__ float As[16][132];   // [k][m], +4 pad keeps float4 alignment
    __shared__ float Bs[16][132];   // [k][n]

    const float* Ab = A  + (long)blockIdx.z * sA;
    const float* Bb = Bm + (long)blockIdx.z * sB;
    float*       Cb = C  + (long)blockIdx.z * sC;

    const int m0  = blockIdx.x * 128;
    const int n0  = blockIdx.y * 128;
    const int tid = threadIdx.x;
    const int wave = tid >> 6, lane = tid & 63;
    const int tm8 = ((wave >> 1) * 8 + (lane >> 3)) * 8;
    const int tn8 = ((wave &  1) * 8 + (lane &  7)) * 8;

    const int rA = tid >> 2;           // 0..63
    const int qA = (tid & 3) << 2;     // 0,4,8,12

    float acc[8][8] = {};

    for (int k0 = 0; k0 < K; k0 += 16) {
        if (k0) __syncthreads();
        if (A_IS_KXM) {
            const int kk = tid >> 5;             // 0..7
            const int mc = (tid & 31) << 2;      // 0..124
            *(float4*)&As[kk][mc]     = *(const float4*)&Ab[(long)(k0 + kk)     * lda + m0 + mc];
            *(float4*)&As[kk + 8][mc] = *(const float4*)&Ab[(long)(k0 + kk + 8) * lda + m0 + mc];
        } else {
            float4 v0 = *(const float4*)&Ab[(long)(m0 + rA)      * lda + k0 + qA];
            float4 v1 = *(const float4*)&Ab[(long)(m0 + rA + 64) * lda + k0 + qA];
            As[qA+0][rA]    = v0.x; As[qA+1][rA]    = v0.y; As[qA+2][rA]    = v0.z; As[qA+3][rA]    = v0.w;
            As[qA+0][rA+64] = v1.x; As[qA+1][rA+64] = v1.y; As[qA+2][rA+64] = v1.z; As[qA+3][rA+64] = v1.w;
        }
        {
            float4 w0 = *(const float4*)&Bb[(long)(n0 + rA)      * ldb + k0 + qA];
            float4 w1 = *(const float4*)&Bb[(long)(n0 + rA + 64) * ldb + k0 + qA];
            Bs[qA+0][rA]    = w0.x; Bs[qA+1][rA]    = w0.y; Bs[qA+2][rA]    = w0.z; Bs[qA+3][rA]    = w0.w;
            Bs[qA+0][rA+64] = w1.x; Bs[qA+1][rA+64] = w1.y; Bs[qA+2][rA+64] = w1.z; Bs[qA+3][rA+64] = w1.w;
        }
        __syncthreads();

        #pragma unroll
        for (int k = 0; k < 16; ++k) {
            float4 a0 = *(const float4*)&As[k][tm8];
            float4 a1 = *(const float4*)&As[k][tm8 + 4];
            float4 b0 = *(const float4*)&Bs[k][tn8];
            float4 b1 = *(const float4*)&Bs[k][tn8 + 4];
            float ar[8] = {a0.x,a0.y,a0.z,a0.w,a1.x,a1.y,a1.z,a1.w};
            float br[8] = {b0.x,b0.y,b0.z,b0.w,b1.x,b1.y,b1.z,b1.w};
            #pragma unroll
            for (int i = 0; i < 8; ++i)
                #pragma unroll
                for (int j = 0; j < 8; ++j)
                    acc[i][j] += ar[i] * br[j];
        }
    }

    #pragma unroll
    for (int i = 0; i < 8; ++i) {
        long row = (long)(m0 + tm8 + i) * ldc + n0 + tn8;
        float4 c0 = make_float4(acc[i][0], acc[i][1], acc[i][2], acc[i][3]);
        float4 c1 = make_float4(acc[i][4], acc[i][5], acc[i][6], acc[i][7]);
        *(float4*)&Cb[row]     = c0;
        *(float4*)&Cb[row + 4] = c1;
    }
}

// ---------------------------------------------------------------------------
// Depthwise causal conv (width 4) + SiLU.  xz layout (B, E, L).
// ---------------------------------------------------------------------------
__global__ __launch_bounds__(256) void conv_silu_k(
    const float* __restrict__ xz, const float* __restrict__ conv_w,
    const float* __restrict__ conv_b, float* __restrict__ xout)
{
    const long gid = (long)blockIdx.x * 256 + threadIdx.x;
    const int  q   = (int)(gid % (L_SZ / 4));
    const long bc  = gid / (L_SZ / 4);
    const int  ch  = (int)(bc % DI);
    const int  b   = (int)(bc / DI);

    const float* row = xz + ((long)b * E_SZ + ch) * L_SZ;
    const int l0 = q * 4;

    float4 cur = *(const float4*)&row[l0];
    float4 prev = q ? *(const float4*)&row[l0 - 4] : make_float4(0.f, 0.f, 0.f, 0.f);

    const float w0 = conv_w[ch*DC+0], w1 = conv_w[ch*DC+1];
    const float w2 = conv_w[ch*DC+2], w3 = conv_w[ch*DC+3];
    const float bias = conv_b[ch];

    float4 o;
    o.x = silu_f(bias + w0*prev.y + w1*prev.z + w2*prev.w + w3*cur.x);
    o.y = silu_f(bias + w0*prev.z + w1*prev.w + w2*cur.x  + w3*cur.y);
    o.z = silu_f(bias + w0*prev.w + w1*cur.x  + w2*cur.y  + w3*cur.z);
    o.w = silu_f(bias + w0*cur.x  + w1*cur.y  + w2*cur.z  + w3*cur.w);

    *(float4*)&xout[((long)b * DI + ch) * L_SZ + l0] = o;
}

// ---------------------------------------------------------------------------
// Direct causal long conv, lag-major with register-sliding x window.
//   y[b,c,l] = sum_{d=0}^{l} k[c,d] * x[b,c,l-d]
// Block = 128 threads = 2 waves; wave wv handles channel 2*blockIdx.y+wv.
// Each wave: 64 lanes x 16 consecutive outputs = l-tile of 1024 at
// l0 = 1024*blockIdx.x.  Lags processed in 256-chunks:
//   Ks[j]   = k[d0+j]                          (wave-uniform broadcast reads)
//   Xs[idx] = x[l0-d0-260+idx], idx in [0,1284), zero-padded below 0
// Xs is bank-swizzled (phys = L + 4*(L>>5)) so the per-lane stride-64B b128
// refill read hits all 8 bank-quads evenly (8 lanes each = 1024B BW floor).
// Per 4-lag step/lane: 64 FMA + 1 dense b128 + 1 broadcast b128 -> VALU-bound.
// Epilogue fuses +D_skip*x and *silu(z).
// ---------------------------------------------------------------------------
#define XSWZ(L) ((L) + ((((L) >> 5)) << 2))

__global__ __launch_bounds__(128) void longconv_k(
    const float* __restrict__ xbuf, const float* __restrict__ xz,
    const float* __restrict__ k_ssm, const float* __restrict__ D_skip,
    float* __restrict__ ybuf)
{
    __shared__ float Xs[2][1444];   // 321 groups + 40 pad groups + 3 spare
    __shared__ float Ks[2][256];

    const int lane = threadIdx.x & 63;
    const int wv   = threadIdx.x >> 6;
    const int l0   = blockIdx.x * 1024;
    const int ch   = blockIdx.y * 2 + wv;
    const int b    = blockIdx.z;

    const float* xrow = xbuf + ((long)b * DI + ch) * L_SZ;
    const float* krow = k_ssm + (long)ch * L_SZ;

    float* XsW = Xs[wv];
    float* KsW = Ks[wv];

    float acc[16];
    #pragma unroll
    for (int c = 0; c < 16; ++c) acc[c] = 0.f;

    const int nchunks = (l0 + 1024) >> 8;   // 4*(tile+1)
    for (int ci = 0; ci < nchunks; ++ci) {
        const int d0  = ci << 8;
        const int w0p = l0 - d0 - 260;      // logical Xs[idx] = x[w0p + idx]

        __syncthreads();
        #pragma unroll 6
        for (int L4 = lane * 4; L4 < 1284; L4 += 256) {
            const int g = w0p + L4;         // multiple of 4
            float4 v = make_float4(0.f, 0.f, 0.f, 0.f);
            if (g >= 0) v = *(const float4*)&xrow[g];
            *(float4*)&XsW[XSWZ(L4)] = v;
        }
        *(float4*)&KsW[lane * 4] = *(const float4*)&krow[d0 + lane * 4];
        __syncthreads();

        // init 20-float register window: logical [16*lane+256, 16*lane+276)
        float w[20];
        #pragma unroll
        for (int q = 0; q < 5; ++q) {
            const int L = 16 * lane + 256 + 4 * q;
            float4 v = *(const float4*)&XsW[XSWZ(L)];
            w[4*q+0] = v.x; w[4*q+1] = v.y; w[4*q+2] = v.z; w[4*q+3] = v.w;
        }

        #pragma unroll 8
        for (int j0 = 0; j0 < 256; j0 += 4) {
            float4 kv = *(const float4*)&KsW[j0];                 // broadcast
            const int Lr = 16 * lane + 252 - j0;                  // next group
            float4 nx = *(const float4*)&XsW[XSWZ(Lr)];           // dense b128

            // lag j' uses w[c - j' + 4]
            #pragma unroll
            for (int c = 0; c < 16; ++c) acc[c] += kv.x * w[c + 4];
            #pragma unroll
            for (int c = 0; c < 16; ++c) acc[c] += kv.y * w[c + 3];
            #pragma unroll
            for (int c = 0; c < 16; ++c) acc[c] += kv.z * w[c + 2];
            #pragma unroll
            for (int c = 0; c < 16; ++c) acc[c] += kv.w * w[c + 1];

            // slide window down by 4
            #pragma unroll
            for (int e = 19; e >= 4; --e) w[e] = w[e - 4];
            w[0] = nx.x; w[1] = nx.y; w[2] = nx.z; w[3] = nx.w;
        }
    }

    // epilogue: (acc + D_skip*x) * silu(z);  z is channel DI+ch of xz
    const float* zrow = xz + ((long)b * E_SZ + DI + ch) * L_SZ;
    float*       yrow = ybuf + ((long)b * DI + ch) * L_SZ;
    const float  Ds   = D_skip[ch];
    const int    lbase = l0 + 16 * lane;

    #pragma unroll
    for (int r = 0; r < 4; ++r) {
        const int l = lbase + 4 * r;
        float4 xv = *(const float4*)&xrow[l];
        float4 zv = *(const float4*)&zrow[l];
        float4 o;
        o.x = (acc[4*r+0] + Ds * xv.x) * silu_f(zv.x);
        o.y = (acc[4*r+1] + Ds * xv.y) * silu_f(zv.y);
        o.z = (acc[4*r+2] + Ds * xv.z) * silu_f(zv.z);
        o.w = (acc[4*r+3] + Ds * xv.w) * silu_f(zv.w);
        *(float4*)&yrow[l] = o;
    }
}

// ---------------------------------------------------------------------------
extern "C" void kernel_launch(void* const* d_in, const int* in_sizes, int n_in,
                              void* d_out, int out_size, void* d_ws, size_t ws_size,
                              hipStream_t stream)
{
    const float* hidden = (const float*)d_in[0];  // (B, L, DM)
    const float* W_in   = (const float*)d_in[1];  // (E, DM)
    const float* conv_w = (const float*)d_in[2];  // (DI, 4)
    const float* conv_b = (const float*)d_in[3];  // (DI)
    const float* k_ssm  = (const float*)d_in[4];  // (DI, L)
    const float* D_skip = (const float*)d_in[5];  // (DI)
    const float* W_out  = (const float*)d_in[6];  // (DM, DI)
    float* out = (float*)d_out;                   // (B, L, DM)

    // workspace: xz (B,E,L) | x (B,DI,L) | y (B,DI,L)  => 256 MiB fp32
    float* xz   = (float*)d_ws;
    float* xbuf = xz   + (size_t)B_SZ * E_SZ * L_SZ;
    float* ybuf = xbuf + (size_t)B_SZ * DI * L_SZ;

    // 1) xz[b,e,l] = sum_d W_in[e,d] * hidden[b,l,d]
    gemm_nt<false><<<dim3(E_SZ/128, L_SZ/128, B_SZ), 256, 0, stream>>>(
        W_in, hidden, xz,
        /*lda*/DM, /*ldb*/DM, /*ldc*/L_SZ,
        /*sA*/0L, /*sB*/(long)L_SZ*DM, /*sC*/(long)E_SZ*L_SZ, /*K*/DM);

    // 2) depthwise causal conv4 + SiLU -> xbuf
    conv_silu_k<<<dim3((unsigned)((long)B_SZ*DI*(L_SZ/4)/256)), 256, 0, stream>>>(
        xz, conv_w, conv_b, xbuf);

    // 3) long causal conv + D_skip + silu(z) gate -> ybuf (B,DI,L)
    longconv_k<<<dim3(L_SZ/1024, DI/2, B_SZ), 128, 0, stream>>>(
        xbuf, xz, k_ssm, D_skip, ybuf);

    // 4) out[b,l,d] = sum_h y[b,h,l] * W_out[d,h]   (A = y stored K x M)
    gemm_nt<true><<<dim3(L_SZ/128, DM/128, B_SZ), 256, 0, stream>>>(
        ybuf, W_out, out,
        /*lda*/L_SZ, /*ldb*/DI, /*ldc*/DM,
        /*sA*/(long)DI*L_SZ, /*sB*/0L, /*sC*/(long)L_SZ*DM, /*K*/DI);
}

// Round 3
// 1548.182 us; speedup vs baseline: 4.1283x; 1.9550x over previous
//
#include <hip/hip_runtime.h>
#include <hip/hip_bf16.h>
#include <math.h>

// Problem constants: B,L,D_MODEL=(2,4096,1024), D_INNER=2048, D_CONV=4
#define B_SZ 2
#define L_SZ 4096
#define DM   1024
#define DI   2048
#define E_SZ 4096
#define DC   4

typedef unsigned short u16;
typedef __attribute__((ext_vector_type(8))) short short8;   // 8 bf16 = 4 VGPRs
typedef __attribute__((ext_vector_type(4))) float f32x4;

__device__ __forceinline__ float silu_f(float v) {
    return v / (1.0f + __expf(-v));
}

// split fp32 -> bf16 hi (truncate) + bf16 lo (truncate of exact residual)
// residual after hi+lo <= 2^-16 relative
__device__ __forceinline__ void split_bf16(float x, u16& h, u16& l) {
    unsigned u  = __float_as_uint(x);
    unsigned hb = u & 0xFFFF0000u;
    h = (u16)(hb >> 16);
    float lf = x - __uint_as_float(hb);    // exact (same-exponent subtract)
    l = (u16)(__float_as_uint(lf) >> 16);
}
__device__ __forceinline__ float bf2f(u16 h) {
    return __uint_as_float(((unsigned)h) << 16);
}

// ---------------------------------------------------------------------------
// Tiled fp32 GEMM (unchanged from R1): C[m,n] = sum_k A[m,k]*B[n,k]
// ---------------------------------------------------------------------------
template<bool A_IS_KXM>
__global__ __launch_bounds__(256) void gemm_nt(
    const float* __restrict__ A, const float* __restrict__ Bm,
    float* __restrict__ C,
    int lda, int ldb, int ldc,
    long sA, long sB, long sC, int K)
{
    __shared__ float As[16][132];
    __shared__ float Bs[16][132];

    const float* Ab = A  + (long)blockIdx.z * sA;
    const float* Bb = Bm + (long)blockIdx.z * sB;
    float*       Cb = C  + (long)blockIdx.z * sC;

    const int m0  = blockIdx.x * 128;
    const int n0  = blockIdx.y * 128;
    const int tid = threadIdx.x;
    const int wave = tid >> 6, lane = tid & 63;
    const int tm8 = ((wave >> 1) * 8 + (lane >> 3)) * 8;
    const int tn8 = ((wave &  1) * 8 + (lane &  7)) * 8;

    const int rA = tid >> 2;
    const int qA = (tid & 3) << 2;

    float acc[8][8] = {};

    for (int k0 = 0; k0 < K; k0 += 16) {
        if (k0) __syncthreads();
        if (A_IS_KXM) {
            const int kk = tid >> 5;
            const int mc = (tid & 31) << 2;
            *(float4*)&As[kk][mc]     = *(const float4*)&Ab[(long)(k0 + kk)     * lda + m0 + mc];
            *(float4*)&As[kk + 8][mc] = *(const float4*)&Ab[(long)(k0 + kk + 8) * lda + m0 + mc];
        } else {
            float4 v0 = *(const float4*)&Ab[(long)(m0 + rA)      * lda + k0 + qA];
            float4 v1 = *(const float4*)&Ab[(long)(m0 + rA + 64) * lda + k0 + qA];
            As[qA+0][rA]    = v0.x; As[qA+1][rA]    = v0.y; As[qA+2][rA]    = v0.z; As[qA+3][rA]    = v0.w;
            As[qA+0][rA+64] = v1.x; As[qA+1][rA+64] = v1.y; As[qA+2][rA+64] = v1.z; As[qA+3][rA+64] = v1.w;
        }
        {
            float4 w0 = *(const float4*)&Bb[(long)(n0 + rA)      * ldb + k0 + qA];
            float4 w1 = *(const float4*)&Bb[(long)(n0 + rA + 64) * ldb + k0 + qA];
            Bs[qA+0][rA]    = w0.x; Bs[qA+1][rA]    = w0.y; Bs[qA+2][rA]    = w0.z; Bs[qA+3][rA]    = w0.w;
            Bs[qA+0][rA+64] = w1.x; Bs[qA+1][rA+64] = w1.y; Bs[qA+2][rA+64] = w1.z; Bs[qA+3][rA+64] = w1.w;
        }
        __syncthreads();

        #pragma unroll
        for (int k = 0; k < 16; ++k) {
            float4 a0 = *(const float4*)&As[k][tm8];
            float4 a1 = *(const float4*)&As[k][tm8 + 4];
            float4 b0 = *(const float4*)&Bs[k][tn8];
            float4 b1 = *(const float4*)&Bs[k][tn8 + 4];
            float ar[8] = {a0.x,a0.y,a0.z,a0.w,a1.x,a1.y,a1.z,a1.w};
            float br[8] = {b0.x,b0.y,b0.z,b0.w,b1.x,b1.y,b1.z,b1.w};
            #pragma unroll
            for (int i = 0; i < 8; ++i)
                #pragma unroll
                for (int j = 0; j < 8; ++j)
                    acc[i][j] += ar[i] * br[j];
        }
    }

    #pragma unroll
    for (int i = 0; i < 8; ++i) {
        long row = (long)(m0 + tm8 + i) * ldc + n0 + tn8;
        *(float4*)&Cb[row]     = make_float4(acc[i][0], acc[i][1], acc[i][2], acc[i][3]);
        *(float4*)&Cb[row + 4] = make_float4(acc[i][4], acc[i][5], acc[i][6], acc[i][7]);
    }
}

// ---------------------------------------------------------------------------
// Depthwise causal conv4 + SiLU; emits x as split bf16 hi/lo pair (B,DI,L).
// ---------------------------------------------------------------------------
__global__ __launch_bounds__(256) void conv_silu_split(
    const float* __restrict__ xz, const float* __restrict__ conv_w,
    const float* __restrict__ conv_b,
    u16* __restrict__ xh_gl, u16* __restrict__ xl_gl)
{
    const long gid = (long)blockIdx.x * 256 + threadIdx.x;
    const int  q   = (int)(gid % (L_SZ / 4));
    const long bc  = gid / (L_SZ / 4);
    const int  ch  = (int)(bc % DI);
    const int  b   = (int)(bc / DI);

    const float* row = xz + ((long)b * E_SZ + ch) * L_SZ;
    const int l0 = q * 4;

    float4 cur  = *(const float4*)&row[l0];
    float4 prev = q ? *(const float4*)&row[l0 - 4] : make_float4(0.f, 0.f, 0.f, 0.f);

    const float w0 = conv_w[ch*DC+0], w1 = conv_w[ch*DC+1];
    const float w2 = conv_w[ch*DC+2], w3 = conv_w[ch*DC+3];
    const float bias = conv_b[ch];

    float o[4];
    o[0] = silu_f(bias + w0*prev.y + w1*prev.z + w2*prev.w + w3*cur.x);
    o[1] = silu_f(bias + w0*prev.z + w1*prev.w + w2*cur.x  + w3*cur.y);
    o[2] = silu_f(bias + w0*prev.w + w1*cur.x  + w2*cur.y  + w3*cur.z);
    o[3] = silu_f(bias + w0*cur.x  + w1*cur.y  + w2*cur.z  + w3*cur.w);

    unsigned long long hp = 0ull, lp = 0ull;
    #pragma unroll
    for (int r = 0; r < 4; ++r) {
        u16 h, l; split_bf16(o[r], h, l);
        hp |= ((unsigned long long)h) << (16*r);
        lp |= ((unsigned long long)l) << (16*r);
    }
    const long base = ((long)b * DI + ch) * L_SZ + l0;
    *(unsigned long long*)&xh_gl[base] = hp;
    *(unsigned long long*)&xl_gl[base] = lp;
}

// ---------------------------------------------------------------------------
// MFMA long causal conv via block-Toeplitz:
//   Y[:,P] = sum_r Kblk(r)·X[:,P-r],  Kblk(r)[i][j]=k[16r+i-j], X[j][Q]=x[16Q+j]
// K=32 MFMA (16x16x32 bf16) stacks r = 2c, 2c+1 per lag-chunk c in [0,128):
//   A[i][j] = k[32c+i-j]        (j<16)  | k[32c+32+i-j]        (j>=16)
//   B[j][p] = x[16P-32c+j]      (j<16)  | x[16P-32c+j-32]      (j>=16)
// One wave per (batch,channel); 16 C-tiles (256 outputs each) live in
// acc regs across the whole c-loop.  Tile t valid iff c <= 8t+7 (causality);
// x left-padded with 256 zeros and k zero-guarded -> exact causal edges.
// 3-pass split-bf16: kh·xh + kh·xl + kl·xh (residual <= 2^-16 rel).
// A built from per-lane global k gathers (8 fp32/chunk, prefetched);
// B read as aligned ds_read_b128 (offset provably ≡ 0 mod 8 elements).
// ---------------------------------------------------------------------------
__global__ __launch_bounds__(128, 2) void longconv_mfma(
    const u16* __restrict__ xh_gl, const u16* __restrict__ xl_gl,
    const float* __restrict__ xz,  const float* __restrict__ k_ssm,
    const float* __restrict__ D_skip, float* __restrict__ ybuf)
{
    __shared__ u16 Xh[2][4352];   // 256 zero-pad + 4096
    __shared__ u16 Xl[2][4352];

    const int lane = threadIdx.x & 63;
    const int wv   = threadIdx.x >> 6;
    const int wc   = blockIdx.x * 2 + wv;     // 0..4095
    const int ch   = wc & (DI - 1);
    const int b    = wc >> 11;

    const u16*   xhr  = xh_gl + ((long)b * DI + ch) * L_SZ;
    const u16*   xlr  = xl_gl + ((long)b * DI + ch) * L_SZ;
    const float* krow = k_ssm + (long)ch * L_SZ;

    u16* XH = Xh[wv];
    u16* XL = Xl[wv];

    // ---- stage x row (hi/lo) into LDS with 256-element zero pad ----
    if (lane < 32) {
        uint4 z = make_uint4(0u, 0u, 0u, 0u);
        *(uint4*)&XH[lane * 8] = z;
        *(uint4*)&XL[lane * 8] = z;
    }
    #pragma unroll
    for (int it = 0; it < 8; ++it) {
        const int idx = it * 64 + lane;                 // 0..511
        *(uint4*)&XH[256 + idx * 8] = ((const uint4*)xhr)[idx];
        *(uint4*)&XL[256 + idx * 8] = ((const uint4*)xlr)[idx];
    }
    __syncthreads();

    // ---- lane geometry ----
    const int m_ = lane & 15;                 // A row i / C col p (by operand)
    const int q_ = lane >> 4;                 // k-quad
    // A-gather offset: k-index = 32c + dq - e
    const int dq = m_ - 8 * q_ + ((q_ >= 2) ? 32 : 0);
    // B LDS element offset (+256t - 32c later); ≡ 0 (mod 8)
    const int xoff_lane = 256 + 16 * m_ + 8 * q_ - ((q_ >= 2) ? 32 : 0);

    f32x4 acc[16];
    #pragma unroll
    for (int t = 0; t < 16; ++t)
        #pragma unroll
        for (int r = 0; r < 4; ++r) acc[t][r] = 0.f;

    // prefetch k window for c=0
    float kn[8];
    #pragma unroll
    for (int e = 0; e < 8; ++e) {
        const int ki = dq - e;
        kn[e] = (ki >= 0) ? krow[ki] : 0.0f;
    }

    for (int c = 0; c < 128; ++c) {
        float kv[8];
        #pragma unroll
        for (int e = 0; e < 8; ++e) kv[e] = kn[e];
        if (c < 127) {
            #pragma unroll
            for (int e = 0; e < 8; ++e) {
                const int ki = 32 * (c + 1) + dq - e;
                kn[e] = (ki >= 0) ? krow[ki] : 0.0f;   // upper bound provably < L
            }
        }

        // build A fragments (hi/lo)
        short8 ah, al;
        #pragma unroll
        for (int e = 0; e < 8; ++e) {
            u16 h, l; split_bf16(kv[e], h, l);
            ah[e] = (short)h; al[e] = (short)l;
        }

        const int xbase = xoff_lane - 32 * c;
        #pragma unroll
        for (int t = 0; t < 16; ++t) {
            if (8 * t >= c - 7) {                       // causality: c <= 8t+7
                short8 bh = *(const short8*)&XH[xbase + 256 * t];
                short8 bl = *(const short8*)&XL[xbase + 256 * t];
                acc[t] = __builtin_amdgcn_mfma_f32_16x16x32_bf16(ah, bh, acc[t], 0, 0, 0);
                acc[t] = __builtin_amdgcn_mfma_f32_16x16x32_bf16(ah, bl, acc[t], 0, 0, 0);
                acc[t] = __builtin_amdgcn_mfma_f32_16x16x32_bf16(al, bh, acc[t], 0, 0, 0);
            }
        }
    }

    // ---- epilogue: y = (conv + D_skip*x) * silu(z) ----
    // C/D layout (m89-verified): col p = lane&15, row i = 4*(lane>>4)+reg
    const float  Ds   = D_skip[ch];
    const float* zrow = xz   + ((long)b * E_SZ + DI + ch) * L_SZ;
    float*       yrow = ybuf + ((long)b * DI + ch) * L_SZ;

    #pragma unroll
    for (int t = 0; t < 16; ++t) {
        const int l0 = 256 * t + 16 * m_ + 4 * q_;
        float4 zv = *(const float4*)&zrow[l0];
        float zt[4] = { zv.x, zv.y, zv.z, zv.w };
        float o[4];
        #pragma unroll
        for (int r = 0; r < 4; ++r) {
            const float xf = bf2f(XH[256 + l0 + r]) + bf2f(XL[256 + l0 + r]);
            o[r] = (acc[t][r] + Ds * xf) * silu_f(zt[r]);
        }
        *(float4*)&yrow[l0] = make_float4(o[0], o[1], o[2], o[3]);
    }
}

// ---------------------------------------------------------------------------
extern "C" void kernel_launch(void* const* d_in, const int* in_sizes, int n_in,
                              void* d_out, int out_size, void* d_ws, size_t ws_size,
                              hipStream_t stream)
{
    const float* hidden = (const float*)d_in[0];  // (B, L, DM)
    const float* W_in   = (const float*)d_in[1];  // (E, DM)
    const float* conv_w = (const float*)d_in[2];  // (DI, 4)
    const float* conv_b = (const float*)d_in[3];  // (DI)
    const float* k_ssm  = (const float*)d_in[4];  // (DI, L)
    const float* D_skip = (const float*)d_in[5];  // (DI)
    const float* W_out  = (const float*)d_in[6];  // (DM, DI)
    float* out = (float*)d_out;                   // (B, L, DM)

    // workspace: xz fp32 (B,E,L) | xh u16 (B,DI,L) | xl u16 | y fp32 (B,DI,L)
    float* xz   = (float*)d_ws;
    u16*   xh   = (u16*)(xz + (size_t)B_SZ * E_SZ * L_SZ);
    u16*   xl   = xh + (size_t)B_SZ * DI * L_SZ;
    float* ybuf = (float*)(xl + (size_t)B_SZ * DI * L_SZ);

    // 1) xz[b,e,l] = sum_d W_in[e,d] * hidden[b,l,d]
    gemm_nt<false><<<dim3(E_SZ/128, L_SZ/128, B_SZ), 256, 0, stream>>>(
        W_in, hidden, xz,
        DM, DM, L_SZ,
        0L, (long)L_SZ*DM, (long)E_SZ*L_SZ, DM);

    // 2) depthwise causal conv4 + SiLU -> split bf16 hi/lo
    conv_silu_split<<<dim3((unsigned)((long)B_SZ*DI*(L_SZ/4)/256)), 256, 0, stream>>>(
        xz, conv_w, conv_b, xh, xl);

    // 3) MFMA long causal conv + D_skip + silu(z) gate -> ybuf (B,DI,L)
    longconv_mfma<<<dim3((B_SZ * DI) / 2), 128, 0, stream>>>(
        xh, xl, xz, k_ssm, D_skip, ybuf);

    // 4) out[b,l,d] = sum_h y[b,h,l] * W_out[d,h]
    gemm_nt<true><<<dim3(L_SZ/128, DM/128, B_SZ), 256, 0, stream>>>(
        ybuf, W_out, out,
        L_SZ, DI, DM,
        (long)DI*L_SZ, 0L, (long)L_SZ*DM, DI);
}

// Round 4
// 675.428 us; speedup vs baseline: 9.4627x; 2.2921x over previous
//
#include <hip/hip_runtime.h>
#include <hip/hip_bf16.h>
#include <math.h>

// Problem constants: B,L,D_MODEL=(2,4096,1024), D_INNER=2048, D_CONV=4
#define B_SZ 2
#define L_SZ 4096
#define DM   1024
#define DI   2048
#define E_SZ 4096
#define DC   4

typedef unsigned short u16;
typedef __attribute__((ext_vector_type(8))) short short8;   // 8 bf16 = 4 VGPRs
typedef __attribute__((ext_vector_type(4))) float f32x4;

__device__ __forceinline__ float silu_f(float v) {
    return v / (1.0f + __expf(-v));
}

// split fp32 -> bf16 hi (truncate) + bf16 lo (truncate of exact residual)
__device__ __forceinline__ void split_bf16(float x, u16& h, u16& l) {
    unsigned u  = __float_as_uint(x);
    unsigned hb = u & 0xFFFF0000u;
    h = (u16)(hb >> 16);
    float lf = x - __uint_as_float(hb);
    l = (u16)(__float_as_uint(lf) >> 16);
}
__device__ __forceinline__ float bf2f(u16 h) {
    return __uint_as_float(((unsigned)h) << 16);
}

// async global->LDS 16B: dest = wave-uniform LDS base + lane*16
__device__ __forceinline__ void gld_lds16(const u16* g, u16* l) {
    __builtin_amdgcn_global_load_lds(
        (const __attribute__((address_space(1))) unsigned int*)g,
        (__attribute__((address_space(3))) unsigned int*)l, 16, 0, 0);
}

// ---------------------------------------------------------------------------
// pack_rm: fp32 row-major (R x K, k-contiguous, ldx) -> fragment-blocked split
// planes H/Lo laid out [K/32][R/16][512]; within a 16x32 block, element
// (m, k=8q+j) sits at (q*16+m)*8+j  == exactly the 16x16x32 MFMA frag order,
// so GEMM staging is contiguous and ds_read_b128 is lane-dense.
// One thread = one 16B chunk per plane (8 consecutive k at fixed row).
// ---------------------------------------------------------------------------
__global__ __launch_bounds__(256) void pack_rm(
    const float* __restrict__ X, u16* __restrict__ H, u16* __restrict__ Lo,
    int ldx, int r16n, long sX, long sOut)
{
    const long cid = (long)blockIdx.x * 256 + threadIdx.x;
    const int  qc  = (int)(cid & 63);
    const long blk = cid >> 6;
    const int  r16 = (int)(blk % r16n);
    const int  k32 = (int)(blk / r16n);
    const int  q = qc >> 4, m = qc & 15;

    const float* src = X + blockIdx.y * sX + (long)(r16 * 16 + m) * ldx + k32 * 32 + q * 8;
    float4 v0 = *(const float4*)src;
    float4 v1 = *(const float4*)(src + 4);
    float v[8] = {v0.x,v0.y,v0.z,v0.w,v1.x,v1.y,v1.z,v1.w};

    u16 hs[8], ls[8];
    #pragma unroll
    for (int j = 0; j < 8; ++j) split_bf16(v[j], hs[j], ls[j]);

    const long o = blockIdx.y * sOut + cid * 8;
    *(uint4*)&H[o]  = *(const uint4*)hs;
    *(uint4*)&Lo[o] = *(const uint4*)ls;
}

// ---------------------------------------------------------------------------
// MFMA split-bf16 GEMM:  C[m,n] = sum_k A[m,k]*B[n,k]  (fp32-accurate via
// 3-pass Ah*Bh + Ah*Bl + Al*Bh).  Operands pre-packed fragment-blocked.
// 128x128 tile, BK=32, 256 thr = 4 waves (2x2 of 64x64), m97-style
// global_load_lds staging (each wave stages one of the 4 tile planes).
// ---------------------------------------------------------------------------
__global__ __launch_bounds__(256) void gemm_mfma(
    const u16* __restrict__ Ah, const u16* __restrict__ Al,
    const u16* __restrict__ Bh, const u16* __restrict__ Bl,
    float* __restrict__ C,
    int r16A, int r16B, long sA, long sB, long sC,
    int ldc, int nk32)
{
    __shared__ alignas(16) u16 sm[4][4096];   // Ah,Al,Bh,Bl 128x32 tiles (8KB each)

    const int tid  = threadIdx.x;
    const int wv   = tid >> 6, lane = tid & 63;
    const long zb  = blockIdx.z;

    const u16* srcs0 = Ah + zb * sA;
    const u16* srcs1 = Al + zb * sA;
    const u16* srcs2 = Bh + zb * sB;
    const u16* srcs3 = Bl + zb * sB;
    const u16* mysrc = (wv == 0) ? srcs0 : (wv == 1) ? srcs1 : (wv == 2) ? srcs2 : srcs3;
    const int  rblk  = (wv < 2) ? blockIdx.x * 8 : blockIdx.y * 8;
    const int  r16c  = (wv < 2) ? r16A : r16B;
    u16* myl = sm[wv];

    const int wr = wv >> 1, wc = wv & 1;

    f32x4 acc[4][4];
    #pragma unroll
    for (int i = 0; i < 4; ++i)
        #pragma unroll
        for (int j = 0; j < 4; ++j)
            #pragma unroll
            for (int r = 0; r < 4; ++r) acc[i][j][r] = 0.f;

    for (int s = 0; s < nk32; ++s) {
        if (s) __syncthreads();
        {
            const u16* g = mysrc + (((long)s * r16c + rblk) << 9) + lane * 8;
            #pragma unroll
            for (int i = 0; i < 8; ++i)
                gld_lds16(g + (i << 9), myl + (i << 9));
        }
        __syncthreads();

        short8 afh[4], afl[4], bfh[4], bfl[4];
        const int aoff = (wr * 4) * 512 + lane * 8;
        const int boff = (wc * 4) * 512 + lane * 8;
        #pragma unroll
        for (int t = 0; t < 4; ++t) {
            afh[t] = *(const short8*)&sm[0][aoff + t * 512];
            afl[t] = *(const short8*)&sm[1][aoff + t * 512];
            bfh[t] = *(const short8*)&sm[2][boff + t * 512];
            bfl[t] = *(const short8*)&sm[3][boff + t * 512];
        }
        #pragma unroll
        for (int i = 0; i < 4; ++i)
            #pragma unroll
            for (int j = 0; j < 4; ++j) {
                acc[i][j] = __builtin_amdgcn_mfma_f32_16x16x32_bf16(afh[i], bfh[j], acc[i][j], 0, 0, 0);
                acc[i][j] = __builtin_amdgcn_mfma_f32_16x16x32_bf16(afh[i], bfl[j], acc[i][j], 0, 0, 0);
                acc[i][j] = __builtin_amdgcn_mfma_f32_16x16x32_bf16(afl[i], bfh[j], acc[i][j], 0, 0, 0);
            }
    }

    // C/D layout: col n = lane&15, row m = 4*(lane>>4)+reg
    const int m_ = lane & 15, q_ = lane >> 4;
    float* Cb = C + zb * sC;
    const int row00 = blockIdx.x * 128 + wr * 64 + q_ * 4;
    const int col0  = blockIdx.y * 128 + wc * 64 + m_;
    #pragma unroll
    for (int i = 0; i < 4; ++i)
        #pragma unroll
        for (int j = 0; j < 4; ++j) {
            const long base = (long)(row00 + i * 16) * ldc + col0 + j * 16;
            #pragma unroll
            for (int r = 0; r < 4; ++r)
                Cb[base + (long)r * ldc] = acc[i][j][r];
        }
}

// ---------------------------------------------------------------------------
// Depthwise causal conv4 + SiLU; emits x as split bf16 hi/lo planes (B,DI,L).
// ---------------------------------------------------------------------------
__global__ __launch_bounds__(256) void conv_silu_split(
    const float* __restrict__ xz, const float* __restrict__ conv_w,
    const float* __restrict__ conv_b,
    u16* __restrict__ xh_gl, u16* __restrict__ xl_gl)
{
    const long gid = (long)blockIdx.x * 256 + threadIdx.x;
    const int  q   = (int)(gid % (L_SZ / 4));
    const long bc  = gid / (L_SZ / 4);
    const int  ch  = (int)(bc % DI);
    const int  b   = (int)(bc / DI);

    const float* row = xz + ((long)b * E_SZ + ch) * L_SZ;
    const int l0 = q * 4;

    float4 cur  = *(const float4*)&row[l0];
    float4 prev = q ? *(const float4*)&row[l0 - 4] : make_float4(0.f, 0.f, 0.f, 0.f);

    const float w0 = conv_w[ch*DC+0], w1 = conv_w[ch*DC+1];
    const float w2 = conv_w[ch*DC+2], w3 = conv_w[ch*DC+3];
    const float bias = conv_b[ch];

    float o[4];
    o[0] = silu_f(bias + w0*prev.y + w1*prev.z + w2*prev.w + w3*cur.x);
    o[1] = silu_f(bias + w0*prev.z + w1*prev.w + w2*cur.x  + w3*cur.y);
    o[2] = silu_f(bias + w0*prev.w + w1*cur.x  + w2*cur.y  + w3*cur.z);
    o[3] = silu_f(bias + w0*cur.x  + w1*cur.y  + w2*cur.z  + w3*cur.w);

    unsigned long long hp = 0ull, lp = 0ull;
    #pragma unroll
    for (int r = 0; r < 4; ++r) {
        u16 h, l; split_bf16(o[r], h, l);
        hp |= ((unsigned long long)h) << (16*r);
        lp |= ((unsigned long long)l) << (16*r);
    }
    const long base = ((long)b * DI + ch) * L_SZ + l0;
    *(unsigned long long*)&xh_gl[base] = hp;
    *(unsigned long long*)&xl_gl[base] = lp;
}

// ---------------------------------------------------------------------------
// MFMA long causal conv (R2-verified), epilogue now writes split-bf16 y
// IN PLACE over the consumed xh/xl rows (each row owned by exactly one wave,
// fully staged to LDS before any overwrite -> safe).
// ---------------------------------------------------------------------------
__global__ __launch_bounds__(128, 2) void longconv_mfma(
    u16* __restrict__ xh_gl, u16* __restrict__ xl_gl,
    const float* __restrict__ xz,  const float* __restrict__ k_ssm,
    const float* __restrict__ D_skip)
{
    __shared__ u16 Xh[2][4352];   // 256 zero-pad + 4096
    __shared__ u16 Xl[2][4352];

    const int lane = threadIdx.x & 63;
    const int wv   = threadIdx.x >> 6;
    const int wc   = blockIdx.x * 2 + wv;
    const int ch   = wc & (DI - 1);
    const int b    = wc >> 11;

    u16*         xhr  = xh_gl + ((long)b * DI + ch) * L_SZ;
    u16*         xlr  = xl_gl + ((long)b * DI + ch) * L_SZ;
    const float* krow = k_ssm + (long)ch * L_SZ;

    u16* XH = Xh[wv];
    u16* XL = Xl[wv];

    if (lane < 32) {
        uint4 z = make_uint4(0u, 0u, 0u, 0u);
        *(uint4*)&XH[lane * 8] = z;
        *(uint4*)&XL[lane * 8] = z;
    }
    #pragma unroll
    for (int it = 0; it < 8; ++it) {
        const int idx = it * 64 + lane;
        *(uint4*)&XH[256 + idx * 8] = ((const uint4*)xhr)[idx];
        *(uint4*)&XL[256 + idx * 8] = ((const uint4*)xlr)[idx];
    }
    __syncthreads();

    const int m_ = lane & 15;
    const int q_ = lane >> 4;
    const int dq = m_ - 8 * q_ + ((q_ >= 2) ? 32 : 0);
    const int xoff_lane = 256 + 16 * m_ + 8 * q_ - ((q_ >= 2) ? 32 : 0);

    f32x4 acc[16];
    #pragma unroll
    for (int t = 0; t < 16; ++t)
        #pragma unroll
        for (int r = 0; r < 4; ++r) acc[t][r] = 0.f;

    float kn[8];
    #pragma unroll
    for (int e = 0; e < 8; ++e) {
        const int ki = dq - e;
        kn[e] = (ki >= 0) ? krow[ki] : 0.0f;
    }

    for (int c = 0; c < 128; ++c) {
        float kv[8];
        #pragma unroll
        for (int e = 0; e < 8; ++e) kv[e] = kn[e];
        if (c < 127) {
            #pragma unroll
            for (int e = 0; e < 8; ++e) {
                const int ki = 32 * (c + 1) + dq - e;
                kn[e] = (ki >= 0) ? krow[ki] : 0.0f;
            }
        }

        short8 ah, al;
        #pragma unroll
        for (int e = 0; e < 8; ++e) {
            u16 h, l; split_bf16(kv[e], h, l);
            ah[e] = (short)h; al[e] = (short)l;
        }

        const int xbase = xoff_lane - 32 * c;
        #pragma unroll
        for (int t = 0; t < 16; ++t) {
            if (8 * t >= c - 7) {
                short8 bh = *(const short8*)&XH[xbase + 256 * t];
                short8 bl = *(const short8*)&XL[xbase + 256 * t];
                acc[t] = __builtin_amdgcn_mfma_f32_16x16x32_bf16(ah, bh, acc[t], 0, 0, 0);
                acc[t] = __builtin_amdgcn_mfma_f32_16x16x32_bf16(ah, bl, acc[t], 0, 0, 0);
                acc[t] = __builtin_amdgcn_mfma_f32_16x16x32_bf16(al, bh, acc[t], 0, 0, 0);
            }
        }
    }

    // epilogue: y = (conv + D_skip*x) * silu(z)  -> split bf16, in-place rows
    const float  Ds   = D_skip[ch];
    const float* zrow = xz + ((long)b * E_SZ + DI + ch) * L_SZ;

    #pragma unroll
    for (int t = 0; t < 16; ++t) {
        const int l0 = 256 * t + 16 * m_ + 4 * q_;
        float4 zv = *(const float4*)&zrow[l0];
        float zt[4] = { zv.x, zv.y, zv.z, zv.w };
        unsigned long long hp = 0ull, lp = 0ull;
        #pragma unroll
        for (int r = 0; r < 4; ++r) {
            const float xf = bf2f(XH[256 + l0 + r]) + bf2f(XL[256 + l0 + r]);
            const float o  = (acc[t][r] + Ds * xf) * silu_f(zt[r]);
            u16 h, l; split_bf16(o, h, l);
            hp |= ((unsigned long long)h) << (16*r);
            lp |= ((unsigned long long)l) << (16*r);
        }
        *(unsigned long long*)&xhr[l0] = hp;
        *(unsigned long long*)&xlr[l0] = lp;
    }
}

// ---------------------------------------------------------------------------
// pack_y: y split planes (B,DI,L) u16 -> GEMM2 A-operand fragment-blocked
// [K/32=64][L/16=256][512] per batch, via LDS transpose tile (32h x 128l).
// ---------------------------------------------------------------------------
__global__ __launch_bounds__(256) void pack_y(
    const u16* __restrict__ Yh, const u16* __restrict__ Yl,
    u16* __restrict__ OH, u16* __restrict__ OL, long sOut)
{
    __shared__ u16 T[2][32][136];
    const int t  = threadIdx.x;
    const int l0 = blockIdx.x * 128;
    const int h0 = blockIdx.y * 32;
    const int b  = blockIdx.z;

    const u16* yb_h = Yh + ((long)b * DI + h0) * L_SZ + l0;
    const u16* yb_l = Yl + ((long)b * DI + h0) * L_SZ + l0;

    #pragma unroll
    for (int i = 0; i < 2; ++i) {
        const int c = t + 256 * i;            // 0..511
        const int row = c >> 4, col = (c & 15) * 8;
        *(uint4*)&T[0][row][col] = *(const uint4*)&yb_h[(long)row * L_SZ + col];
        *(uint4*)&T[1][row][col] = *(const uint4*)&yb_l[(long)row * L_SZ + col];
    }
    __syncthreads();

    u16* outs[2] = { OH + b * sOut, OL + b * sOut };
    #pragma unroll
    for (int p = 0; p < 2; ++p) {
        #pragma unroll
        for (int i = 0; i < 2; ++i) {
            const int c = t + 256 * i;        // 0..511
            const int r16b = c >> 6, qc = c & 63;
            const int q = qc >> 4, m = qc & 15;
            const int l = r16b * 16 + m;
            u16 vals[8];
            #pragma unroll
            for (int j = 0; j < 8; ++j) vals[j] = T[p][q * 8 + j][l];
            const long o = ((long)(blockIdx.y * 256 + blockIdx.x * 8 + r16b) << 9) + qc * 8;
            *(uint4*)&outs[p][o] = *(const uint4*)vals;
        }
    }
}

// ---------------------------------------------------------------------------
extern "C" void kernel_launch(void* const* d_in, const int* in_sizes, int n_in,
                              void* d_out, int out_size, void* d_ws, size_t ws_size,
                              hipStream_t stream)
{
    const float* hidden = (const float*)d_in[0];  // (B, L, DM)
    const float* W_in   = (const float*)d_in[1];  // (E, DM)
    const float* conv_w = (const float*)d_in[2];  // (DI, 4)
    const float* conv_b = (const float*)d_in[3];  // (DI)
    const float* k_ssm  = (const float*)d_in[4];  // (DI, L)
    const float* D_skip = (const float*)d_in[5];  // (DI)
    const float* W_out  = (const float*)d_in[6];  // (DM, DI)
    float* out = (float*)d_out;                   // (B, L, DM)

    // ---- workspace layout (bytes) ----
    // xz fp32 (B,E,L)            @ 0          134,217,728
    // xh u16  (B,DI,L)           @ 134,217,728  33,554,432   (becomes y-hi)
    // xl u16  (B,DI,L)           @ 167,772,160  33,554,432   (becomes y-lo)
    // slotA: Win packs -> Wout packs @ 201,326,592  16,777,216
    // slotB: hidden packs        @ 218,103,808  33,554,432
    // yA packs alias xz x-halves (dead after longconv)
    char* ws = (char*)d_ws;
    float* xz  = (float*)ws;
    u16*   xh  = (u16*)(ws + 134217728);
    u16*   xl  = (u16*)(ws + 167772160);
    u16*   WinH  = (u16*)(ws + 201326592);
    u16*   WinL  = WinH + 4194304;            // 32*256*512
    u16*   WoutH = (u16*)(ws + 201326592);    // reused after GEMM1
    u16*   WoutL = WoutH + 2097152;           // 64*64*512
    u16*   hidH  = (u16*)(ws + 218103808);
    u16*   hidL  = hidH + 8388608;            // per-plane both batches
    u16*   yAh   = (u16*)ws;                  // aliases xz; per-batch stride 33,554,432 elems
    u16*   yAl   = yAh + 8388608;

    // 1) pack W_in (R=E=4096,K=DM=1024) and hidden (per b: R=L,K=DM)
    pack_rm<<<dim3(2048, 1), 256, 0, stream>>>(W_in, WinH, WinL, DM, 256, 0L, 0L);
    pack_rm<<<dim3(2048, B_SZ), 256, 0, stream>>>(hidden, hidH, hidL, DM, 256,
        (long)L_SZ * DM, 4194304L);

    // 2) GEMM1: xz[b,e,l] = sum_d W_in[e,d]*hidden[b,l,d]
    gemm_mfma<<<dim3(32, 32, B_SZ), 256, 0, stream>>>(
        WinH, WinL, hidH, hidL, xz,
        256, 256, 0L, 4194304L, (long)E_SZ * L_SZ, L_SZ, 32);

    // 3) depthwise causal conv4 + SiLU -> split bf16 x
    conv_silu_split<<<dim3((unsigned)((long)B_SZ*DI*(L_SZ/4)/256)), 256, 0, stream>>>(
        xz, conv_w, conv_b, xh, xl);

    // 4) MFMA long causal conv + D_skip + silu(z) -> y split, in-place in xh/xl
    longconv_mfma<<<dim3((B_SZ * DI) / 2), 128, 0, stream>>>(
        xh, xl, xz, k_ssm, D_skip);

    // 5) pack W_out (R=DM=1024,K=DI=2048) into slotA (Win packs now dead)
    pack_rm<<<dim3(1024, 1), 256, 0, stream>>>(W_out, WoutH, WoutL, DI, 64, 0L, 0L);

    // 6) pack y -> GEMM2 A-operand blocked (into dead xz x-half region)
    pack_y<<<dim3(32, 64, B_SZ), 256, 0, stream>>>(
        xh, xl, yAh, yAl, 33554432L);

    // 7) GEMM2: out[b,l,d] = sum_h y[b,h,l]*W_out[d,h]
    gemm_mfma<<<dim3(32, 8, B_SZ), 256, 0, stream>>>(
        yAh, yAl, WoutH, WoutL, out,
        256, 64, 33554432L, 0L, (long)L_SZ * DM, DM, 64);
}